// Round 8
// baseline (155.515 us; speedup 1.0000x reference)
//
#include <hip/hip_runtime.h>

#define NB 32
#define NT 512
#define ND 80
#define NK 16
#define NP 64

// D*log(2*pi)
#define C_DLOG2PI (80.0f * 1.837877066409345f)

#define REG_CHUNKS 16
#define APAD 88    // T_sh pitch in bf16 elems (16B-aligned rows)

typedef __attribute__((ext_vector_type(8))) short bf16x8;
typedef __attribute__((ext_vector_type(4))) short s16x4;
typedef __attribute__((ext_vector_type(4))) float f32x4;

__device__ inline unsigned short f2bf(float f) {
    unsigned u = __float_as_uint(f);
    unsigned r = (u + 0x7fffu + ((u >> 16) & 1u)) >> 16;  // RNE
    return (unsigned short)r;
}

__global__ void zero_out_kernel(float* out) { out[0] = 0.0f; }

// ---------------------------------------------------------------------------
// Triangular inversion v4.
// R7 post-mortem: chunked state DID reach registers (VGPR=132) but the kernel
// stayed latency-bound at 1 wave/SIMD: ~3900 wave-uniform GLOBAL L reads
// (~200cyc each) + 8-way-conflicted V_sh reloads (517K conflicts). Fix:
//  - L staged once in LDS (coalesced), all solve reads are conflict-free
//    uniform LDS broadcasts (~12cyc b128 issue, pipelineable).
//  - v history kept ENTIRELY in registers as v[5][16]; the 5 chunks are
//    macro-expanded straight-line code (guaranteed static indices), all
//    inner loops <=16-trip (the regime the unroller demonstrably honors).
//  - logf/div hoisted: lane-parallel diagonal pass computes logdet and
//    invd_sh[80] once per block.
// ---------------------------------------------------------------------------
__global__ __launch_bounds__(128) void inv_kernel(
    const float* __restrict__ L_subj,
    const int* __restrict__ sids,
    unsigned short* __restrict__ linv_ws,   // [NB*NK][ND*ND] bf16
    float* __restrict__ logdet_ws)          // [NB*NK]
{
    const int bk  = blockIdx.x;
    const int b   = bk >> 4;
    const int k   = bk & 15;
    const int tid = threadIdx.x;
    const int c   = tid;     // column; threads c>=ND compute zeros, never store
    const int s   = __builtin_amdgcn_readfirstlane(sids[b]);
    const float* __restrict__ Lg = L_subj + (((size_t)s * NK + k) * ND * ND);

    __shared__ __align__(16) float Ls[ND * ND];               // 25.6 KB
    __shared__ float invd_sh[ND];
    __shared__ float ld_part[2];
    __shared__ __align__(16) unsigned short T_sh[ND * APAD];  // 14.1 KB

    // coalesced stage of L into LDS (1600 float4)
    {
        const float4* src = (const float4*)Lg;
        float4* dst = (float4*)Ls;
        for (int i = tid; i < ND * ND / 4; i += 128) dst[i] = src[i];
    }
    // lane-parallel diagonal pass: invd + logdet (once per block, not per thread)
    float lg = 0.0f;
    if (tid < ND) {
        float d = Lg[tid * ND + tid];
        invd_sh[tid] = 1.0f / d;
        lg = logf(d);
    }
    #pragma unroll
    for (int off = 32; off > 0; off >>= 1) lg += __shfl_down(lg, off);
    if ((tid & 63) == 0) ld_part[tid >> 6] = lg;
    __syncthreads();
    if (tid == 0) logdet_ws[bk] = 2.0f * (ld_part[0] + ld_part[1]);

    // ----- solve: column c of Linv, v[5][16] register-resident -----
    float v[5][16];

#define CHUNK(M) do {                                                          \
    float acc_[16];                                                            \
    _Pragma("unroll")                                                          \
    for (int r = 0; r < 16; ++r) acc_[r] = (((M)*16 + r) == c) ? 1.0f : 0.0f;  \
    _Pragma("unroll")                                                          \
    for (int m = 0; m < (M); ++m) {                                            \
        _Pragma("unroll")                                                      \
        for (int r = 0; r < 16; ++r) {                                         \
            const float* Lr_ = &Ls[((M)*16 + r) * ND + m * 16];                \
            float a0_ = 0.f, a1_ = 0.f;                                        \
            _Pragma("unroll")                                                  \
            for (int q = 0; q < 16; q += 2) {                                  \
                a0_ += Lr_[q + 0] * v[m][q + 0];                               \
                a1_ += Lr_[q + 1] * v[m][q + 1];                               \
            }                                                                  \
            acc_[r] -= a0_ + a1_;                                              \
        }                                                                      \
    }                                                                          \
    _Pragma("unroll")                                                          \
    for (int r = 0; r < 16; ++r) {                                             \
        const float* Lr_ = &Ls[((M)*16 + r) * ND + (M)*16];                    \
        float a_ = acc_[r];                                                    \
        _Pragma("unroll")                                                      \
        for (int q = 0; q < 16; ++q)                                           \
            if (q < r) a_ -= Lr_[q] * v[(M)][q];                               \
        float val_ = a_ * invd_sh[(M)*16 + r];                                 \
        v[(M)][r] = val_;                                                      \
        if (c < ND) T_sh[((M)*16 + r) * APAD + c] = f2bf(val_);                \
    }                                                                          \
} while (0)

    CHUNK(0);
    CHUNK(1);
    CHUNK(2);
    CHUNK(3);
    CHUNK(4);
#undef CHUNK

    __syncthreads();

    // coalesced bf16 write-out: 80 rows * 80 bf16 = 800 uint4
    uint4* dst = (uint4*)(linv_ws + (size_t)bk * (ND * ND));
    for (int i = tid; i < ND * ND / 8; i += 128) {
        int n  = i / 10;
        int c8 = (i % 10) * 8;
        dst[i] = *(const uint4*)&T_sh[n * APAD + c8];
    }
}

// ---------------------------------------------------------------------------
// Block = (b, ttile of 128, k). Y = R(128x80) * Linv^T  via mfma 16x16x32 bf16
// (K padded to 96; last K-step lane-zeroed). mahal_t = sum_n Y[t][n]^2 via
// per-reg squares + butterfly-xor over lane bits 0..3. Then gamma-weighted
// accumulation of (C + logdet + mahal).
// ---------------------------------------------------------------------------
__global__ __launch_bounds__(256) void gemm_kernel(
    const float* __restrict__ x,
    const float* __restrict__ mu_subj,
    const float* __restrict__ gamma,
    const int* __restrict__ sids,
    const unsigned short* __restrict__ linv_ws,
    const float* __restrict__ logdet_ws,
    float* __restrict__ out)
{
    const int bx = blockIdx.x;          // 2048 = 32 b * 4 ttile * 16 k
    const int k  = bx & 15;
    const int tt = (bx >> 4) & 3;
    const int b  = bx >> 6;
    const int bk = b * NK + k;
    const int t0 = tt * 128;
    const int tid  = threadIdx.x;
    const int lane = tid & 63;
    const int wv   = tid >> 6;
    const int m    = lane & 15;
    const int g    = lane >> 4;
    const int s    = __builtin_amdgcn_readfirstlane(sids[b]);

    __shared__ unsigned short A_sh[128 * APAD];  // R tile, bf16
    __shared__ unsigned short B_sh[ND * APAD];   // Linv rows, bf16

    // --- stage A: R[r][j] = bf16(x[b][t0+r][j] - mu[s][k][j]), 2 thr/row ---
    {
        const int r = tid >> 1;
        const int h = tid & 1;
        const float4* xp = (const float4*)(x + ((size_t)(b * NT + t0 + r)) * ND + h * 40);
        const float4* mp = (const float4*)(mu_subj + ((size_t)(s * NK + k)) * ND + h * 40);
        #pragma unroll
        for (int q = 0; q < 10; ++q) {
            float4 xv = xp[q];
            float4 mv = mp[q];
            s16x4 pk;
            pk.x = (short)f2bf(xv.x - mv.x);
            pk.y = (short)f2bf(xv.y - mv.y);
            pk.z = (short)f2bf(xv.z - mv.z);
            pk.w = (short)f2bf(xv.w - mv.w);
            *(s16x4*)&A_sh[r * APAD + h * 40 + q * 4] = pk;
        }
    }
    // --- stage B: Linv bf16 rows (row n holds Linv[n][0..79]) ---
    {
        const uint4* src = (const uint4*)(linv_ws + (size_t)bk * (ND * ND));
        for (int i = tid; i < ND * ND / 8; i += 256) {
            int n  = i / 10;
            int c8 = (i % 10) * 8;
            *(uint4*)&B_sh[n * APAD + c8] = src[i];
        }
    }
    __syncthreads();

    // --- MFMA: per wave, 32 t-rows x 80 cols, K = 96 (3 steps of 32) ---
    f32x4 acc[2][5];
    #pragma unroll
    for (int mt = 0; mt < 2; ++mt)
        #pragma unroll
        for (int nt = 0; nt < 5; ++nt)
            acc[mt][nt] = (f32x4){0.f, 0.f, 0.f, 0.f};

    const bf16x8 zf = {0, 0, 0, 0, 0, 0, 0, 0};
    #pragma unroll
    for (int ks = 0; ks < 3; ++ks) {
        const int kbase = ks * 32 + g * 8;
        bf16x8 af[2], bfr[5];
        if (kbase < ND) {
            af[0] = *(const bf16x8*)&A_sh[(wv * 32 + m) * APAD + kbase];
            af[1] = *(const bf16x8*)&A_sh[(wv * 32 + 16 + m) * APAD + kbase];
            #pragma unroll
            for (int nt = 0; nt < 5; ++nt)
                bfr[nt] = *(const bf16x8*)&B_sh[(nt * 16 + m) * APAD + kbase];
        } else {
            af[0] = zf; af[1] = zf;
            #pragma unroll
            for (int nt = 0; nt < 5; ++nt) bfr[nt] = zf;
        }
        #pragma unroll
        for (int mt = 0; mt < 2; ++mt)
            #pragma unroll
            for (int nt = 0; nt < 5; ++nt)
                acc[mt][nt] = __builtin_amdgcn_mfma_f32_16x16x32_bf16(
                    af[mt], bfr[nt], acc[mt][nt], 0, 0, 0);
    }

    // --- epilogue: mahal per t, gamma weighting ---
    const float ldet_c = logdet_ws[bk] + C_DLOG2PI;
    float local = 0.0f;
    #pragma unroll
    for (int mt = 0; mt < 2; ++mt) {
        float p0 = 0.f, p1 = 0.f, p2 = 0.f, p3 = 0.f;
        #pragma unroll
        for (int nt = 0; nt < 5; ++nt) {
            p0 += acc[mt][nt][0] * acc[mt][nt][0];
            p1 += acc[mt][nt][1] * acc[mt][nt][1];
            p2 += acc[mt][nt][2] * acc[mt][nt][2];
            p3 += acc[mt][nt][3] * acc[mt][nt][3];
        }
        #pragma unroll
        for (int mask = 1; mask < 16; mask <<= 1) {
            p0 += __shfl_xor(p0, mask);
            p1 += __shfl_xor(p1, mask);
            p2 += __shfl_xor(p2, mask);
            p3 += __shfl_xor(p3, mask);
        }
        if (m < 4) {
            float mm = (m == 0) ? p0 : (m == 1) ? p1 : (m == 2) ? p2 : p3;
            int t = t0 + wv * 32 + mt * 16 + g * 4 + m;
            float gam = gamma[((size_t)(b * NT + t)) * NK + k];
            local += gam * (mm + ldet_c);
        }
    }

    // block reduce + atomic
    __shared__ float partial[4];
    #pragma unroll
    for (int off = 32; off > 0; off >>= 1) local += __shfl_down(local, off);
    if (lane == 0) partial[wv] = local;
    __syncthreads();
    if (tid == 0) {
        float sum = partial[0] + partial[1] + partial[2] + partial[3];
        atomicAdd(out, sum * (0.5f / (NB * NT)));
    }
}

// ---------------------------------------------------------------------------
// Regularization: grid (chunk, subject).
// ---------------------------------------------------------------------------
__global__ __launch_bounds__(256) void reg_kernel(
    const float* __restrict__ mu_pop,
    const float* __restrict__ L_pop,
    const float* __restrict__ mu_subj,
    const float* __restrict__ L_subj,
    const int* __restrict__ sids,
    float* __restrict__ out)
{
    const int p   = blockIdx.y;
    const int c   = blockIdx.x;
    const int tid = threadIdx.x;

    __shared__ float scale_sh;
    __shared__ int   present_sh;
    __shared__ float partial[4];

    if (tid == 0) {
        unsigned long long seen = 0ull;
        int present = 0;
        for (int b = 0; b < NB; ++b) {
            int sb = sids[b];
            seen |= (1ull << sb);
            present |= (sb == p) ? 1 : 0;
        }
        present_sh = present;
        scale_sh = (float)__popcll(seen) * (1.0f / (float)NP);
    }
    __syncthreads();
    if (!present_sh) return;  // uniform exit

    float acc = 0.0f;
    {
        const float4* Ls4 = reinterpret_cast<const float4*>(L_subj + (size_t)p * NK * ND * ND);
        const float4* Lp4 = reinterpret_cast<const float4*>(L_pop);
        const int n4 = NK * ND * ND / 4;
        for (int i = c * 256 + tid; i < n4; i += REG_CHUNKS * 256) {
            float4 a = Ls4[i];
            float4 bq = Lp4[i];
            float dx = a.x - bq.x, dy = a.y - bq.y, dz = a.z - bq.z, dw = a.w - bq.w;
            acc += dx * dx + dy * dy + dz * dz + dw * dw;
        }
    }
    if (c == 0) {
        const float4* ms4 = reinterpret_cast<const float4*>(mu_subj + (size_t)p * NK * ND);
        const float4* mp4 = reinterpret_cast<const float4*>(mu_pop);
        const int n4 = NK * ND / 4;
        for (int i = tid; i < n4; i += 256) {
            float4 a = ms4[i];
            float4 bq = mp4[i];
            float dx = a.x - bq.x, dy = a.y - bq.y, dz = a.z - bq.z, dw = a.w - bq.w;
            acc += dx * dx + dy * dy + dz * dz + dw * dw;
        }
    }

    #pragma unroll
    for (int off = 32; off > 0; off >>= 1) acc += __shfl_down(acc, off);
    int wave = tid >> 6;
    if ((tid & 63) == 0) partial[wave] = acc;
    __syncthreads();
    if (tid == 0) {
        float total = partial[0] + partial[1] + partial[2] + partial[3];
        atomicAdd(out, scale_sh * 0.05f * total);  // lambda/2 = 0.05 both terms
    }
}

extern "C" void kernel_launch(void* const* d_in, const int* in_sizes, int n_in,
                              void* d_out, int out_size, void* d_ws, size_t ws_size,
                              hipStream_t stream) {
    (void)in_sizes; (void)n_in; (void)ws_size; (void)out_size;
    const float* x       = (const float*)d_in[0];
    const float* mu_pop  = (const float*)d_in[1];
    const float* L_pop   = (const float*)d_in[2];
    const float* mu_subj = (const float*)d_in[3];
    const float* L_subj  = (const float*)d_in[4];
    const float* gamma   = (const float*)d_in[5];
    const int*   sids    = (const int*)d_in[6];
    float* out = (float*)d_out;

    unsigned short* linv_ws = (unsigned short*)d_ws;                       // 6.55 MB
    float* logdet_ws = (float*)((char*)d_ws + (size_t)NB * NK * ND * ND * 2);

    hipLaunchKernelGGL(zero_out_kernel, dim3(1), dim3(1), 0, stream, out);
    hipLaunchKernelGGL(inv_kernel, dim3(NB * NK), dim3(128), 0, stream,
                       L_subj, sids, linv_ws, logdet_ws);
    hipLaunchKernelGGL(gemm_kernel, dim3(NB * 4 * NK), dim3(256), 0, stream,
                       x, mu_subj, gamma, sids, linv_ws, logdet_ws, out);
    hipLaunchKernelGGL(reg_kernel, dim3(REG_CHUNKS, NP), dim3(256), 0, stream,
                       mu_pop, L_pop, mu_subj, L_subj, sids, out);
}

// Round 10
// 82.437 us; speedup vs baseline: 1.8865x; 1.8865x over previous
//
#include <hip/hip_runtime.h>

#define NB 32
#define NT 512
#define ND 80
#define NK 16
#define NP 64

// D*log(2*pi)
#define C_DLOG2PI (80.0f * 1.837877066409345f)

#define REG_CHUNKS 16
#define APAD 88    // gemm LDS pitch in bf16 elems (16B-aligned rows)

typedef __attribute__((ext_vector_type(8))) short bf16x8;
typedef __attribute__((ext_vector_type(4))) short s16x4;
typedef __attribute__((ext_vector_type(4))) float f32x4;

__device__ inline unsigned short f2bf(float f) {
    unsigned u = __float_as_uint(f);
    unsigned r = (u + 0x7fffu + ((u >> 16) & 1u)) >> 16;  // RNE
    return (unsigned short)r;
}

__device__ inline unsigned pack2bf(float a, float b) {
    return (unsigned)f2bf(a) | ((unsigned)f2bf(b) << 16);
}

__global__ void zero_out_kernel(float* out) { out[0] = 0.0f; }

// ---------------------------------------------------------------------------
// Triangular inversion v5 = R7's register structure + LDS-everything.
// Ledger: R7 (chunked vseg/acc/vj, runtime base loop) was the ONLY variant
// whose state stayed in VGPRs (132, no spill). Its costs were (a) ~3.2K
// serialized wave-uniform GLOBAL L reads and (b) 8-way-conflicted V_sh
// float4 reloads (stride 84: 517K conflicts). R8's all-in-regs attempt
// spilled (VGPR=256 cap, 200MB scratch). This version:
//   - L staged once in LDS, coalesced; solve reads are same-address
//     broadcasts (conflict-free).
//   - V_sh TRANSPOSED to [i][c] (pitch 128): lane accesses hit bank c%32,
//     2 lanes/bank = free. Thread c only touches column c -> no syncs.
//   - T_sh dropped; bf16 conversion at writeout directly from V_sh.
// ---------------------------------------------------------------------------
__global__ __launch_bounds__(128) void inv_kernel(
    const float* __restrict__ L_subj,
    const int* __restrict__ sids,
    unsigned short* __restrict__ linv_ws,   // [NB*NK][ND*ND] bf16 row-major
    float* __restrict__ logdet_ws)          // [NB*NK]
{
    const int bk  = blockIdx.x;
    const int b   = bk >> 4;
    const int k   = bk & 15;
    const int tid = threadIdx.x;
    const int c   = tid;     // column; threads c>=ND compute garbage, never read back
    const int s   = __builtin_amdgcn_readfirstlane(sids[b]);
    const float* __restrict__ Lg = L_subj + (((size_t)s * NK + k) * ND * ND);

    __shared__ __align__(16) float Ls[ND * ND];      // 25.6 KB, row-major L
    __shared__ __align__(16) float V_sh[ND * 128];   // 41 KB, [row i][col c]
    __shared__ float invd_sh[ND];
    __shared__ float ld_part[2];

    // coalesced stage of L into LDS (1600 float4)
    {
        const float4* src = (const float4*)Lg;
        float4* dst = (float4*)Ls;
        for (int i = tid; i < ND * ND / 4; i += 128) dst[i] = src[i];
    }
    // lane-parallel diagonal pass: invd + logdet (global reads, no Ls dep)
    float lg = 0.0f;
    if (tid < ND) {
        float d = Lg[tid * ND + tid];
        invd_sh[tid] = 1.0f / d;
        lg = logf(d);
    }
    #pragma unroll
    for (int off = 32; off > 0; off >>= 1) lg += __shfl_down(lg, off);
    if ((tid & 63) == 0) ld_part[tid >> 6] = lg;
    __syncthreads();
    if (tid == 0) logdet_ws[bk] = 2.0f * (ld_part[0] + ld_part[1]);

    // ----- solve column c of Linv: L v = e_c, chunked by 16 rows -----
    for (int base = 0; base < ND; base += 16) {
        float acc[16];
        #pragma unroll
        for (int r = 0; r < 16; ++r) acc[r] = ((base + r) == c) ? 1.0f : 0.0f;

        // part 1: dot rows [base..base+15] against completed chunks
        for (int jt = 0; jt < base; jt += 16) {
            float vj[16];
            #pragma unroll
            for (int q = 0; q < 16; ++q) vj[q] = V_sh[(jt + q) * 128 + c];  // bank c%32, free
            #pragma unroll
            for (int r = 0; r < 16; ++r) {
                const float* Lrow = &Ls[(base + r) * ND + jt];  // uniform -> broadcast
                float a0 = 0.f, a1 = 0.f;
                #pragma unroll
                for (int q = 0; q < 16; q += 2) {
                    a0 += Lrow[q + 0] * vj[q + 0];
                    a1 += Lrow[q + 1] * vj[q + 1];
                }
                acc[r] -= a0 + a1;
            }
        }

        // part 2: within-chunk triangular recurrence (vseg register-resident)
        float vseg[16];
        #pragma unroll
        for (int r = 0; r < 16; ++r) {
            const int I = base + r;
            const float* Lrow = &Ls[I * ND + base];
            float a = acc[r];
            #pragma unroll
            for (int q = 0; q < 16; ++q)
                if (q < r) a -= Lrow[q] * vseg[q];   // q,r static -> folds
            const float val = a * invd_sh[I];
            vseg[r] = val;
            V_sh[I * 128 + c] = val;                 // bank c%32, free
        }
    }

    __syncthreads();

    // writeout: Linv row-major bf16, 800 uint4, coalesced
    uint4* dst = (uint4*)(linv_ws + (size_t)bk * (ND * ND));
    for (int i = tid; i < ND * ND / 8; i += 128) {
        int n  = i / 10;
        int c8 = (i % 10) * 8;
        const float* vp = &V_sh[n * 128 + c8];
        uint4 o;
        o.x = pack2bf(vp[0], vp[1]);
        o.y = pack2bf(vp[2], vp[3]);
        o.z = pack2bf(vp[4], vp[5]);
        o.w = pack2bf(vp[6], vp[7]);
        dst[i] = o;
    }
}

// ---------------------------------------------------------------------------
// Block = (b, ttile of 128, k). Y = R(128x80) * Linv^T  via mfma 16x16x32 bf16
// (K padded to 96; last K-step lane-zeroed). mahal_t = sum_n Y[t][n]^2 via
// per-reg squares + butterfly-xor over lane bits 0..3. Then gamma-weighted
// accumulation of (C + logdet + mahal).
// ---------------------------------------------------------------------------
__global__ __launch_bounds__(256) void gemm_kernel(
    const float* __restrict__ x,
    const float* __restrict__ mu_subj,
    const float* __restrict__ gamma,
    const int* __restrict__ sids,
    const unsigned short* __restrict__ linv_ws,
    const float* __restrict__ logdet_ws,
    float* __restrict__ out)
{
    const int bx = blockIdx.x;          // 2048 = 32 b * 4 ttile * 16 k
    const int k  = bx & 15;
    const int tt = (bx >> 4) & 3;
    const int b  = bx >> 6;
    const int bk = b * NK + k;
    const int t0 = tt * 128;
    const int tid  = threadIdx.x;
    const int lane = tid & 63;
    const int wv   = tid >> 6;
    const int m    = lane & 15;
    const int g    = lane >> 4;
    const int s    = __builtin_amdgcn_readfirstlane(sids[b]);

    __shared__ unsigned short A_sh[128 * APAD];  // R tile, bf16
    __shared__ unsigned short B_sh[ND * APAD];   // Linv rows, bf16

    // --- stage A: R[r][j] = bf16(x[b][t0+r][j] - mu[s][k][j]), 2 thr/row ---
    {
        const int r = tid >> 1;
        const int h = tid & 1;
        const float4* xp = (const float4*)(x + ((size_t)(b * NT + t0 + r)) * ND + h * 40);
        const float4* mp = (const float4*)(mu_subj + ((size_t)(s * NK + k)) * ND + h * 40);
        #pragma unroll
        for (int q = 0; q < 10; ++q) {
            float4 xv = xp[q];
            float4 mv = mp[q];
            s16x4 pk;
            pk.x = (short)f2bf(xv.x - mv.x);
            pk.y = (short)f2bf(xv.y - mv.y);
            pk.z = (short)f2bf(xv.z - mv.z);
            pk.w = (short)f2bf(xv.w - mv.w);
            *(s16x4*)&A_sh[r * APAD + h * 40 + q * 4] = pk;
        }
    }
    // --- stage B: Linv bf16 rows (row n holds Linv[n][0..79]) ---
    {
        const uint4* src = (const uint4*)(linv_ws + (size_t)bk * (ND * ND));
        for (int i = tid; i < ND * ND / 8; i += 256) {
            int n  = i / 10;
            int c8 = (i % 10) * 8;
            *(uint4*)&B_sh[n * APAD + c8] = src[i];
        }
    }
    __syncthreads();

    // --- MFMA: per wave, 32 t-rows x 80 cols, K = 96 (3 steps of 32) ---
    f32x4 acc[2][5];
    #pragma unroll
    for (int mt = 0; mt < 2; ++mt)
        #pragma unroll
        for (int nt = 0; nt < 5; ++nt)
            acc[mt][nt] = (f32x4){0.f, 0.f, 0.f, 0.f};

    const bf16x8 zf = {0, 0, 0, 0, 0, 0, 0, 0};
    #pragma unroll
    for (int ks = 0; ks < 3; ++ks) {
        const int kbase = ks * 32 + g * 8;
        bf16x8 af[2], bfr[5];
        if (kbase < ND) {
            af[0] = *(const bf16x8*)&A_sh[(wv * 32 + m) * APAD + kbase];
            af[1] = *(const bf16x8*)&A_sh[(wv * 32 + 16 + m) * APAD + kbase];
            #pragma unroll
            for (int nt = 0; nt < 5; ++nt)
                bfr[nt] = *(const bf16x8*)&B_sh[(nt * 16 + m) * APAD + kbase];
        } else {
            af[0] = zf; af[1] = zf;
            #pragma unroll
            for (int nt = 0; nt < 5; ++nt) bfr[nt] = zf;
        }
        #pragma unroll
        for (int mt = 0; mt < 2; ++mt)
            #pragma unroll
            for (int nt = 0; nt < 5; ++nt)
                acc[mt][nt] = __builtin_amdgcn_mfma_f32_16x16x32_bf16(
                    af[mt], bfr[nt], acc[mt][nt], 0, 0, 0);
    }

    // --- epilogue: mahal per t, gamma weighting ---
    const float ldet_c = logdet_ws[bk] + C_DLOG2PI;
    float local = 0.0f;
    #pragma unroll
    for (int mt = 0; mt < 2; ++mt) {
        float p0 = 0.f, p1 = 0.f, p2 = 0.f, p3 = 0.f;
        #pragma unroll
        for (int nt = 0; nt < 5; ++nt) {
            p0 += acc[mt][nt][0] * acc[mt][nt][0];
            p1 += acc[mt][nt][1] * acc[mt][nt][1];
            p2 += acc[mt][nt][2] * acc[mt][nt][2];
            p3 += acc[mt][nt][3] * acc[mt][nt][3];
        }
        #pragma unroll
        for (int mask = 1; mask < 16; mask <<= 1) {
            p0 += __shfl_xor(p0, mask);
            p1 += __shfl_xor(p1, mask);
            p2 += __shfl_xor(p2, mask);
            p3 += __shfl_xor(p3, mask);
        }
        if (m < 4) {
            float mm = (m == 0) ? p0 : (m == 1) ? p1 : (m == 2) ? p2 : p3;
            int t = t0 + wv * 32 + mt * 16 + g * 4 + m;
            float gam = gamma[((size_t)(b * NT + t)) * NK + k];
            local += gam * (mm + ldet_c);
        }
    }

    // block reduce + atomic
    __shared__ float partial[4];
    #pragma unroll
    for (int off = 32; off > 0; off >>= 1) local += __shfl_down(local, off);
    if (lane == 0) partial[wv] = local;
    __syncthreads();
    if (tid == 0) {
        float sum = partial[0] + partial[1] + partial[2] + partial[3];
        atomicAdd(out, sum * (0.5f / (NB * NT)));
    }
}

// ---------------------------------------------------------------------------
// Regularization: grid (chunk, subject).
// ---------------------------------------------------------------------------
__global__ __launch_bounds__(256) void reg_kernel(
    const float* __restrict__ mu_pop,
    const float* __restrict__ L_pop,
    const float* __restrict__ mu_subj,
    const float* __restrict__ L_subj,
    const int* __restrict__ sids,
    float* __restrict__ out)
{
    const int p   = blockIdx.y;
    const int c   = blockIdx.x;
    const int tid = threadIdx.x;

    __shared__ float scale_sh;
    __shared__ int   present_sh;
    __shared__ float partial[4];

    if (tid == 0) {
        unsigned long long seen = 0ull;
        int present = 0;
        for (int b = 0; b < NB; ++b) {
            int sb = sids[b];
            seen |= (1ull << sb);
            present |= (sb == p) ? 1 : 0;
        }
        present_sh = present;
        scale_sh = (float)__popcll(seen) * (1.0f / (float)NP);
    }
    __syncthreads();
    if (!present_sh) return;  // uniform exit

    float acc = 0.0f;
    {
        const float4* Ls4 = reinterpret_cast<const float4*>(L_subj + (size_t)p * NK * ND * ND);
        const float4* Lp4 = reinterpret_cast<const float4*>(L_pop);
        const int n4 = NK * ND * ND / 4;
        for (int i = c * 256 + tid; i < n4; i += REG_CHUNKS * 256) {
            float4 a = Ls4[i];
            float4 bq = Lp4[i];
            float dx = a.x - bq.x, dy = a.y - bq.y, dz = a.z - bq.z, dw = a.w - bq.w;
            acc += dx * dx + dy * dy + dz * dz + dw * dw;
        }
    }
    if (c == 0) {
        const float4* ms4 = reinterpret_cast<const float4*>(mu_subj + (size_t)p * NK * ND);
        const float4* mp4 = reinterpret_cast<const float4*>(mu_pop);
        const int n4 = NK * ND / 4;
        for (int i = tid; i < n4; i += 256) {
            float4 a = ms4[i];
            float4 bq = mp4[i];
            float dx = a.x - bq.x, dy = a.y - bq.y, dz = a.z - bq.z, dw = a.w - bq.w;
            acc += dx * dx + dy * dy + dz * dz + dw * dw;
        }
    }

    #pragma unroll
    for (int off = 32; off > 0; off >>= 1) acc += __shfl_down(acc, off);
    int wave = tid >> 6;
    if ((tid & 63) == 0) partial[wave] = acc;
    __syncthreads();
    if (tid == 0) {
        float total = partial[0] + partial[1] + partial[2] + partial[3];
        atomicAdd(out, scale_sh * 0.05f * total);  // lambda/2 = 0.05 both terms
    }
}

extern "C" void kernel_launch(void* const* d_in, const int* in_sizes, int n_in,
                              void* d_out, int out_size, void* d_ws, size_t ws_size,
                              hipStream_t stream) {
    (void)in_sizes; (void)n_in; (void)ws_size; (void)out_size;
    const float* x       = (const float*)d_in[0];
    const float* mu_pop  = (const float*)d_in[1];
    const float* L_pop   = (const float*)d_in[2];
    const float* mu_subj = (const float*)d_in[3];
    const float* L_subj  = (const float*)d_in[4];
    const float* gamma   = (const float*)d_in[5];
    const int*   sids    = (const int*)d_in[6];
    float* out = (float*)d_out;

    unsigned short* linv_ws = (unsigned short*)d_ws;                       // 6.55 MB
    float* logdet_ws = (float*)((char*)d_ws + (size_t)NB * NK * ND * ND * 2);

    hipLaunchKernelGGL(zero_out_kernel, dim3(1), dim3(1), 0, stream, out);
    hipLaunchKernelGGL(inv_kernel, dim3(NB * NK), dim3(128), 0, stream,
                       L_subj, sids, linv_ws, logdet_ws);
    hipLaunchKernelGGL(gemm_kernel, dim3(NB * 4 * NK), dim3(256), 0, stream,
                       x, mu_subj, gamma, sids, linv_ws, logdet_ws, out);
    hipLaunchKernelGGL(reg_kernel, dim3(REG_CHUNKS, NP), dim3(256), 0, stream,
                       mu_pop, L_pop, mu_subj, L_subj, sids, out);
}